// Round 1
// baseline (1071.601 us; speedup 1.0000x reference)
//
#include <hip/hip_runtime.h>

// Problem constants
#define BSZ 256   // batch
#define TT  512   // timesteps
#define II  512   // input dim
#define HH  1024  // hidden
#define OO  128   // output
#define BH  262144  // BSZ*HH

// GEMM tiling
#define BM 128
#define BN 128
#define BK 32
#define LDA 40  // padded LDS row stride (shorts): 40*2=80B, 16B-aligned rows, 2-way bank alias (free)

typedef short bfrag8 __attribute__((ext_vector_type(8)));
typedef float f32x4  __attribute__((ext_vector_type(4)));
typedef short s16x4  __attribute__((ext_vector_type(4)));

__device__ __forceinline__ unsigned short f2bf(float f) {
    union { float f; unsigned int u; } c; c.f = f;
    unsigned int u = c.u;
    unsigned int r = u + 0x7fffu + ((u >> 16) & 1u);  // RNE
    return (unsigned short)(r >> 16);
}
__device__ __forceinline__ float bf2f(unsigned short h) {
    union { unsigned int u; float f; } c; c.u = ((unsigned int)h) << 16;
    return c.f;
}

// ---------------------------------------------------------------------------
// Split W_branch (NB,I,HB) fp32 -> W_hiT/W_loT [h][i] bf16 (h = n*HB + o)
// ---------------------------------------------------------------------------
__global__ __launch_bounds__(256) void split_w(const float* __restrict__ Wb,
                                               unsigned short* __restrict__ Whi,
                                               unsigned short* __restrict__ Wlo) {
    int idx = blockIdx.x * 256 + threadIdx.x;      // 0..524287  (NB*I*HB)
    int n = idx >> 17;                              // I*HB = 131072
    int rem = idx & 131071;
    int i = rem >> 8;                               // HB = 256
    int o = rem & 255;
    int h = (n << 8) + o;
    float w = Wb[idx];
    unsigned short hi = f2bf(w);
    float fh = bf2f(hi);
    unsigned short lo = f2bf(w - fh);
    Whi[(size_t)h * II + i] = hi;
    Wlo[(size_t)h * II + i] = lo;
}

// ---------------------------------------------------------------------------
// Init scan state (ws is poisoned each call)
// ---------------------------------------------------------------------------
__global__ __launch_bounds__(256) void init_state(const float* __restrict__ v0,
                                                  float* __restrict__ d, float* __restrict__ v,
                                                  float* __restrict__ s, float* __restrict__ a) {
    int i = blockIdx.x * 256 + threadIdx.x;
    d[i] = 0.0f; v[i] = v0[i]; s[i] = 0.0f; a[i] = 0.0f;
}

// ---------------------------------------------------------------------------
// Split-bf16 GEMM: U[tl][b][h] = sum_i X[b, t0+tl, i] * W[i][h]
// m = b*Tc + tl (b-major within chunk). 3-product fp32 emulation via bf16 MFMA.
// ---------------------------------------------------------------------------
__global__ __launch_bounds__(256, 2) void gemm_split(
    const float* __restrict__ X, const unsigned short* __restrict__ Whi,
    const unsigned short* __restrict__ Wlo, float* __restrict__ U,
    int t0, int lgTc)
{
    __shared__ __align__(16) short Ah[BM * LDA];
    __shared__ __align__(16) short Al[BM * LDA];
    __shared__ __align__(16) short Bh[BN * LDA];
    __shared__ __align__(16) short Bl[BN * LDA];

    const int n_tile = blockIdx.x;          // 0..7  (fastest -> XCD-pinned column)
    const int m_tile = blockIdx.y;
    const int m0 = m_tile * BM;
    const int h0 = n_tile * BN;
    const int tid = threadIdx.x;
    const int lane = tid & 63;
    const int wave = tid >> 6;
    const int wm = wave & 1, wn = wave >> 1;
    const int l16 = lane & 15, q = lane >> 4;

    f32x4 acc[4][4];
#pragma unroll
    for (int i = 0; i < 4; ++i)
#pragma unroll
        for (int j = 0; j < 4; ++j)
#pragma unroll
            for (int r = 0; r < 4; ++r) acc[i][j][r] = 0.0f;

    // staging index precompute
    const int fr = tid & 7;        // float4 index within A row (8 per 32-float row)
    const int r0 = tid >> 3;       // 0..31
    const int cB = tid & 3;        // 16B chunk within B row (4 per 64B row)
    const int nB = tid >> 2;       // 0..63

    for (int k0 = 0; k0 < II; k0 += BK) {
        // ---- stage A (fp32 -> bf16 hi/lo in-register) ----
#pragma unroll
        for (int p = 0; p < 4; ++p) {
            int r = r0 + p * 32;
            int m = m0 + r;
            int bb = m >> lgTc;
            int tl = m - (bb << lgTc);
            const float4* src = (const float4*)(X + ((size_t)(bb * TT + t0 + tl)) * II + k0 + fr * 4);
            float4 val = *src;
            float fv[4] = { val.x, val.y, val.z, val.w };
            s16x4 hi4, lo4;
#pragma unroll
            for (int j = 0; j < 4; ++j) {
                unsigned short h = f2bf(fv[j]);
                float fh = bf2f(h);
                unsigned short l = f2bf(fv[j] - fh);
                hi4[j] = (short)h; lo4[j] = (short)l;
            }
            *(s16x4*)&Ah[r * LDA + fr * 4] = hi4;
            *(s16x4*)&Al[r * LDA + fr * 4] = lo4;
        }
        // ---- stage B (pure copy, pre-split/transposed) ----
#pragma unroll
        for (int p = 0; p < 2; ++p) {
            int n = nB + p * 64;
            *(uint4*)&Bh[n * LDA + cB * 8] = *(const uint4*)(Whi + (size_t)(h0 + n) * II + k0 + cB * 8);
            *(uint4*)&Bl[n * LDA + cB * 8] = *(const uint4*)(Wlo + (size_t)(h0 + n) * II + k0 + cB * 8);
        }
        __syncthreads();

        bfrag8 ah[4], al[4], bh[4], bl[4];
#pragma unroll
        for (int i = 0; i < 4; ++i) {
            int ra = (wm * 64 + i * 16 + l16) * LDA + q * 8;
            ah[i] = *(const bfrag8*)&Ah[ra];
            al[i] = *(const bfrag8*)&Al[ra];
            int rb = (wn * 64 + i * 16 + l16) * LDA + q * 8;
            bh[i] = *(const bfrag8*)&Bh[rb];
            bl[i] = *(const bfrag8*)&Bl[rb];
        }
#pragma unroll
        for (int im = 0; im < 4; ++im)
#pragma unroll
            for (int in = 0; in < 4; ++in) {
                f32x4 c = acc[im][in];
                c = __builtin_amdgcn_mfma_f32_16x16x32_bf16(ah[im], bh[in], c, 0, 0, 0);
                c = __builtin_amdgcn_mfma_f32_16x16x32_bf16(ah[im], bl[in], c, 0, 0, 0);
                c = __builtin_amdgcn_mfma_f32_16x16x32_bf16(al[im], bh[in], c, 0, 0, 0);
                acc[im][in] = c;
            }
        __syncthreads();
    }

    // epilogue: C/D layout col = lane&15, row = (lane>>4)*4 + r
#pragma unroll
    for (int im = 0; im < 4; ++im) {
        int rowb = wm * 64 + im * 16 + q * 4;
#pragma unroll
        for (int r = 0; r < 4; ++r) {
            int m = m0 + rowb + r;
            int bb = m >> lgTc;
            int tl = m - (bb << lgTc);
            size_t base = ((size_t)tl * BSZ + bb) * HH + h0 + wn * 64 + l16;
#pragma unroll
            for (int in = 0; in < 4; ++in)
                U[base + in * 16] = acc[im][in][r];
        }
    }
}

// ---------------------------------------------------------------------------
// Scan chunk: one thread per (b,h); d,v,s,acc recurrence over Tc timesteps
// ---------------------------------------------------------------------------
__global__ __launch_bounds__(256) void scan_chunk(const float* __restrict__ U,
    const float* __restrict__ tau_n, const float* __restrict__ tau_m,
    float* __restrict__ dS, float* __restrict__ vS,
    float* __restrict__ sS, float* __restrict__ aS, int t0, int Tc)
{
    int idx = blockIdx.x * 256 + threadIdx.x;  // b*H + h
    int h = idx & (HH - 1);
    float beta  = 1.0f / (1.0f + expf(-tau_n[h]));   // tau_n flat (NB,HB) == h
    float alpha = 1.0f / (1.0f + expf(-tau_m[h]));
    float ob = 1.0f - beta, oa = 1.0f - alpha;
    float dd = dS[idx], vv = vS[idx], ss = sS[idx], aa = aS[idx];
    const float* Up = U + idx;
#pragma unroll 4
    for (int tl = 0; tl < Tc; ++tl) {
        float u = Up[(size_t)tl << 18];   // stride B*H = 262144
        dd = beta * dd + ob * u;
        vv = alpha * vv + oa * dd - ss;   // uses previous s; V_TH = 1
        ss = (vv > 1.0f) ? 1.0f : 0.0f;   // spike(v - 1 > 0)
        aa += ((t0 + tl) >= (TT / 2)) ? ss : 0.0f;
    }
    dS[idx] = dd; vS[idx] = vv; sS[idx] = ss; aS[idx] = aa;
}

// ---------------------------------------------------------------------------
// out[b][o] = sum_h acc[b][h] * W_out[h][o] + b_out[o]
// ---------------------------------------------------------------------------
__global__ __launch_bounds__(128) void out_gemm(const float* __restrict__ acc,
    const float* __restrict__ Wout, const float* __restrict__ bout,
    float* __restrict__ out)
{
    __shared__ float a_s[HH];
    int b = blockIdx.x, o = threadIdx.x;
    for (int i = o; i < HH; i += 128) a_s[i] = acc[b * HH + i];
    __syncthreads();
    float sum = bout[o];
#pragma unroll 8
    for (int h = 0; h < HH; ++h) sum = fmaf(a_s[h], Wout[h * OO + o], sum);
    out[b * OO + o] = sum;
}

// ---------------------------------------------------------------------------
extern "C" void kernel_launch(void* const* d_in, const int* in_sizes, int n_in,
                              void* d_out, int out_size, void* d_ws, size_t ws_size,
                              hipStream_t stream) {
    const float* x     = (const float*)d_in[0];
    const float* v0    = (const float*)d_in[1];
    const float* Wb    = (const float*)d_in[2];
    const float* tau_n = (const float*)d_in[3];
    const float* tau_m = (const float*)d_in[4];
    const float* Wout  = (const float*)d_in[5];
    const float* bout  = (const float*)d_in[6];
    float* out = (float*)d_out;

    // workspace layout (1 MiB units)
    char* ws = (char*)d_ws;
    unsigned short* Whi = (unsigned short*)(ws);                 // 1 MiB
    unsigned short* Wlo = (unsigned short*)(ws + (1ll << 20));   // 1 MiB
    float* dS = (float*)(ws + (2ll << 20));
    float* vS = (float*)(ws + (3ll << 20));
    float* sS = (float*)(ws + (4ll << 20));
    float* aS = (float*)(ws + (5ll << 20));
    float* U  = (float*)(ws + (6ll << 20));

    long long avail = (long long)ws_size - (6ll << 20);
    int Tc = 512;  // U chunk = Tc MiB
    while (Tc > 16 && (long long)Tc * (1ll << 20) > avail) Tc >>= 1;
    int lgTc = 31 - __builtin_clz((unsigned)Tc);

    split_w<<<2048, 256, 0, stream>>>(Wb, Whi, Wlo);
    init_state<<<BH / 256, 256, 0, stream>>>(v0, dS, vS, sS, aS);

    for (int t0 = 0; t0 < TT; t0 += Tc) {
        dim3 grid(HH / BN, (BSZ * Tc) / BM);  // n fastest -> XCD-pinned columns, L3 reuse of X
        gemm_split<<<grid, 256, 0, stream>>>(x, Whi, Wlo, U, t0, lgTc);
        scan_chunk<<<BH / 256, 256, 0, stream>>>(U, tau_n, tau_m, dS, vS, sS, aS, t0, Tc);
    }
    out_gemm<<<BSZ, 128, 0, stream>>>(aS, Wout, bout, out);
}

// Round 2
// 1032.373 us; speedup vs baseline: 1.0380x; 1.0380x over previous
//
#include <hip/hip_runtime.h>
#include <hip/hip_bf16.h>

// Problem constants
#define BSZ 256   // batch
#define TT  512   // timesteps
#define II  512   // input dim
#define HH  1024  // hidden
#define OO  128   // output
#define BH  262144  // BSZ*HH

// GEMM tiling
#define BM 128
#define BN 128
#define BK 32
#define LDA 40  // padded LDS row stride (shorts): 80B rows, 16B-aligned, 2-way bank alias (free per m136)

typedef short bfrag8 __attribute__((ext_vector_type(8)));
typedef float f32x4  __attribute__((ext_vector_type(4)));
typedef short s16x4  __attribute__((ext_vector_type(4)));

__device__ __forceinline__ unsigned short f2bf(float f) {
    union { float f; unsigned int u; } c; c.f = f;
    unsigned int u = c.u;
    unsigned int r = u + 0x7fffu + ((u >> 16) & 1u);  // RNE
    return (unsigned short)(r >> 16);
}
__device__ __forceinline__ float bf2f(unsigned short h) {
    union { unsigned int u; float f; } c; c.u = ((unsigned int)h) << 16;
    return c.f;
}

// Split a float pair into bf16 hi/lo pairs using packed cvt (v_cvt_pk_bf16_f32)
__device__ __forceinline__ void split2(float f0, float f1, s16x4* hi_dst, s16x4* lo_dst, int off) {
    __hip_bfloat162 h2 = __float22bfloat162_rn(make_float2(f0, f1));
    float r0 = f0 - __bfloat162float(h2.x);
    float r1 = f1 - __bfloat162float(h2.y);
    __hip_bfloat162 l2 = __float22bfloat162_rn(make_float2(r0, r1));
    union { __hip_bfloat162 b; int i; } ch, cl;
    ch.b = h2; cl.b = l2;
    ((int*)hi_dst)[off] = ch.i;
    ((int*)lo_dst)[off] = cl.i;
}

// ---------------------------------------------------------------------------
// Fused setup: split W_branch (NB,I,HB) fp32 -> W_hiT/W_loT [h][i] bf16, and
// init scan state (ws is poisoned each call).
// ---------------------------------------------------------------------------
__global__ __launch_bounds__(256) void setup_k(const float* __restrict__ Wb,
                                               const float* __restrict__ v0,
                                               unsigned short* __restrict__ Whi,
                                               unsigned short* __restrict__ Wlo,
                                               float* __restrict__ dS, float* __restrict__ vS,
                                               float* __restrict__ sS, float* __restrict__ aS) {
    int idx = blockIdx.x * 256 + threadIdx.x;      // 0..524287  (NB*I*HB)
    int n = idx >> 17;                              // I*HB = 131072
    int rem = idx & 131071;
    int i = rem >> 8;                               // HB = 256
    int o = rem & 255;
    int h = (n << 8) + o;
    float w = Wb[idx];
    unsigned short hi = f2bf(w);
    float fh = bf2f(hi);
    unsigned short lo = f2bf(w - fh);
    Whi[(size_t)h * II + i] = hi;
    Wlo[(size_t)h * II + i] = lo;
    if (idx < BH) {
        dS[idx] = 0.0f; vS[idx] = v0[idx]; sS[idx] = 0.0f; aS[idx] = 0.0f;
    }
}

// ---------------------------------------------------------------------------
// Split-bf16 GEMM: U[tl][b][h] = sum_i X[b, t0+tl, i] * W[i][h]
// m = b*Tc + tl (b-major within chunk). 3-product fp32 emulation via bf16 MFMA.
// ---------------------------------------------------------------------------
__global__ __launch_bounds__(256, 4) void gemm_split(
    const float* __restrict__ X, const unsigned short* __restrict__ Whi,
    const unsigned short* __restrict__ Wlo, float* __restrict__ U,
    int t0, int lgTc)
{
    __shared__ __align__(16) short Ah[BM * LDA];
    __shared__ __align__(16) short Al[BM * LDA];
    __shared__ __align__(16) short Bh[BN * LDA];
    __shared__ __align__(16) short Bl[BN * LDA];

    const int n_tile = blockIdx.x;          // 0..7  (fastest -> XCD-pinned column)
    const int m_tile = blockIdx.y;
    const int m0 = m_tile * BM;
    const int h0 = n_tile * BN;
    const int tid = threadIdx.x;
    const int lane = tid & 63;
    const int wave = tid >> 6;
    const int wm = wave & 1, wn = wave >> 1;
    const int l16 = lane & 15, q = lane >> 4;

    f32x4 acc[4][4];
#pragma unroll
    for (int i = 0; i < 4; ++i)
#pragma unroll
        for (int j = 0; j < 4; ++j)
#pragma unroll
            for (int r = 0; r < 4; ++r) acc[i][j][r] = 0.0f;

    // staging index precompute
    const int fr = tid & 7;        // float4 index within A row (8 per 32-float row)
    const int r0 = tid >> 3;       // 0..31
    const int cB = tid & 3;        // 16B chunk within B row (4 per 64B row)
    const int nB = tid >> 2;       // 0..63

    for (int k0 = 0; k0 < II; k0 += BK) {
        // ---- stage A (fp32 -> bf16 hi/lo in-register, packed cvt) ----
#pragma unroll
        for (int p = 0; p < 4; ++p) {
            int r = r0 + p * 32;
            int m = m0 + r;
            int bb = m >> lgTc;
            int tl = m - (bb << lgTc);
            const float4* src = (const float4*)(X + ((size_t)(bb * TT + t0 + tl)) * II + k0 + fr * 4);
            float4 val = *src;
            s16x4 hi4, lo4;
            split2(val.x, val.y, &hi4, &lo4, 0);
            split2(val.z, val.w, &hi4, &lo4, 1);
            *(s16x4*)&Ah[r * LDA + fr * 4] = hi4;
            *(s16x4*)&Al[r * LDA + fr * 4] = lo4;
        }
        // ---- stage B (pure copy, pre-split/transposed) ----
#pragma unroll
        for (int p = 0; p < 2; ++p) {
            int n = nB + p * 64;
            *(uint4*)&Bh[n * LDA + cB * 8] = *(const uint4*)(Whi + (size_t)(h0 + n) * II + k0 + cB * 8);
            *(uint4*)&Bl[n * LDA + cB * 8] = *(const uint4*)(Wlo + (size_t)(h0 + n) * II + k0 + cB * 8);
        }
        __syncthreads();

        bfrag8 ah[4], al[4], bh[4], bl[4];
#pragma unroll
        for (int i = 0; i < 4; ++i) {
            int ra = (wm * 64 + i * 16 + l16) * LDA + q * 8;
            ah[i] = *(const bfrag8*)&Ah[ra];
            al[i] = *(const bfrag8*)&Al[ra];
            int rb = (wn * 64 + i * 16 + l16) * LDA + q * 8;
            bh[i] = *(const bfrag8*)&Bh[rb];
            bl[i] = *(const bfrag8*)&Bl[rb];
        }
#pragma unroll
        for (int im = 0; im < 4; ++im)
#pragma unroll
            for (int in = 0; in < 4; ++in) {
                f32x4 c = acc[im][in];
                c = __builtin_amdgcn_mfma_f32_16x16x32_bf16(ah[im], bh[in], c, 0, 0, 0);
                c = __builtin_amdgcn_mfma_f32_16x16x32_bf16(ah[im], bl[in], c, 0, 0, 0);
                c = __builtin_amdgcn_mfma_f32_16x16x32_bf16(al[im], bh[in], c, 0, 0, 0);
                acc[im][in] = c;
            }
        __syncthreads();
    }

    // epilogue: C/D layout col = lane&15, row = (lane>>4)*4 + r
#pragma unroll
    for (int im = 0; im < 4; ++im) {
        int rowb = wm * 64 + im * 16 + q * 4;
#pragma unroll
        for (int r = 0; r < 4; ++r) {
            int m = m0 + rowb + r;
            int bb = m >> lgTc;
            int tl = m - (bb << lgTc);
            size_t base = ((size_t)tl * BSZ + bb) * HH + h0 + wn * 64 + l16;
#pragma unroll
            for (int in = 0; in < 4; ++in)
                U[base + in * 16] = acc[im][in][r];
        }
    }
}

// ---------------------------------------------------------------------------
// Scan chunk: one thread per 4 consecutive (b,h); float4 loads, depth-8
// software pipeline so >=8 wave-loads stay in flight (BW-bound, not latency).
// ---------------------------------------------------------------------------
__global__ __launch_bounds__(256) void scan_chunk(const float4* __restrict__ U4,
    const float* __restrict__ tau_n, const float* __restrict__ tau_m,
    float4* __restrict__ dS, float4* __restrict__ vS,
    float4* __restrict__ sS, float4* __restrict__ aS, int t0, int Tc)
{
    int tix = blockIdx.x * 256 + threadIdx.x;  // float4 index: 0..65535
    int hb = (tix << 2) & (HH - 1);
    float beta[4], alpha[4], ob[4], oa[4];
#pragma unroll
    for (int j = 0; j < 4; ++j) {
        beta[j]  = 1.0f / (1.0f + __expf(-tau_n[hb + j]));
        alpha[j] = 1.0f / (1.0f + __expf(-tau_m[hb + j]));
        ob[j] = 1.0f - beta[j]; oa[j] = 1.0f - alpha[j];
    }
    float4 d4 = dS[tix], v4 = vS[tix], s4 = sS[tix], a4 = aS[tix];
    float dd[4] = { d4.x, d4.y, d4.z, d4.w };
    float vv[4] = { v4.x, v4.y, v4.z, v4.w };
    float ss[4] = { s4.x, s4.y, s4.z, s4.w };
    float aa[4] = { a4.x, a4.y, a4.z, a4.w };

    const float4* Up = U4 + tix;   // per-t stride = BH/4 = 65536 float4
    float4 ubuf[8];
#pragma unroll
    for (int j = 0; j < 8; ++j) ubuf[j] = Up[(size_t)j << 16];

    for (int tg = 0; tg < Tc; tg += 8) {
#pragma unroll
        for (int j = 0; j < 8; ++j) {
            float4 u4 = ubuf[j];
            int tn = tg + 8 + j;
            if (tn < Tc) ubuf[j] = Up[(size_t)tn << 16];
            float uu[4] = { u4.x, u4.y, u4.z, u4.w };
            float msk = ((t0 + tg + j) >= (TT / 2)) ? 1.0f : 0.0f;
#pragma unroll
            for (int c = 0; c < 4; ++c) {
                dd[c] = beta[c] * dd[c] + ob[c] * uu[c];
                vv[c] = alpha[c] * vv[c] + oa[c] * dd[c] - ss[c];  // prev s; V_TH=1
                ss[c] = (vv[c] > 1.0f) ? 1.0f : 0.0f;
                aa[c] += msk * ss[c];
            }
        }
    }
    dS[tix] = make_float4(dd[0], dd[1], dd[2], dd[3]);
    vS[tix] = make_float4(vv[0], vv[1], vv[2], vv[3]);
    sS[tix] = make_float4(ss[0], ss[1], ss[2], ss[3]);
    aS[tix] = make_float4(aa[0], aa[1], aa[2], aa[3]);
}

// ---------------------------------------------------------------------------
// out[b][o] = sum_h acc[b][h] * W_out[h][o] + b_out[o]
// 256 threads: (o:128) x (h-half:2), LDS combine.
// ---------------------------------------------------------------------------
__global__ __launch_bounds__(256) void out_gemm(const float* __restrict__ acc,
    const float* __restrict__ Wout, const float* __restrict__ bout,
    float* __restrict__ out)
{
    __shared__ float a_s[HH];
    __shared__ float partial[OO];
    int b = blockIdx.x;
    int o = threadIdx.x & (OO - 1);
    int half = threadIdx.x >> 7;
    for (int i = threadIdx.x; i < HH; i += 256) a_s[i] = acc[b * HH + i];
    __syncthreads();
    float sum = half ? 0.0f : bout[o];
    const float* Wp = Wout + (size_t)half * 512 * OO + o;
    const float* ap = a_s + half * 512;
#pragma unroll 8
    for (int h = 0; h < 512; ++h) sum = fmaf(ap[h], Wp[(size_t)h * OO], sum);
    if (half) partial[o] = sum;
    __syncthreads();
    if (!half) out[b * OO + o] = sum + partial[o];
}

// ---------------------------------------------------------------------------
extern "C" void kernel_launch(void* const* d_in, const int* in_sizes, int n_in,
                              void* d_out, int out_size, void* d_ws, size_t ws_size,
                              hipStream_t stream) {
    const float* x     = (const float*)d_in[0];
    const float* v0    = (const float*)d_in[1];
    const float* Wb    = (const float*)d_in[2];
    const float* tau_n = (const float*)d_in[3];
    const float* tau_m = (const float*)d_in[4];
    const float* Wout  = (const float*)d_in[5];
    const float* bout  = (const float*)d_in[6];
    float* out = (float*)d_out;

    // workspace layout (1 MiB units)
    char* ws = (char*)d_ws;
    unsigned short* Whi = (unsigned short*)(ws);                 // 1 MiB
    unsigned short* Wlo = (unsigned short*)(ws + (1ll << 20));   // 1 MiB
    float* dS = (float*)(ws + (2ll << 20));
    float* vS = (float*)(ws + (3ll << 20));
    float* sS = (float*)(ws + (4ll << 20));
    float* aS = (float*)(ws + (5ll << 20));
    float* U  = (float*)(ws + (6ll << 20));

    long long avail = (long long)ws_size - (6ll << 20);
    int Tc = 512;  // U chunk = Tc MiB
    while (Tc > 16 && (long long)Tc * (1ll << 20) > avail) Tc >>= 1;
    int lgTc = 31 - __builtin_clz((unsigned)Tc);

    setup_k<<<2048, 256, 0, stream>>>(Wb, v0, Whi, Wlo, dS, vS, sS, aS);

    for (int t0 = 0; t0 < TT; t0 += Tc) {
        dim3 grid(HH / BN, (BSZ * Tc) / BM);  // n fastest -> XCD-pinned columns, L3 reuse of X
        gemm_split<<<grid, 256, 0, stream>>>(x, Whi, Wlo, U, t0, lgTc);
        scan_chunk<<<BH / 1024, 256, 0, stream>>>((const float4*)U, tau_n, tau_m,
                                                  (float4*)dS, (float4*)vS, (float4*)sS, (float4*)aS,
                                                  t0, Tc);
    }
    out_gemm<<<BSZ, 256, 0, stream>>>(aS, Wout, bout, out);
}

// Round 3
// 983.902 us; speedup vs baseline: 1.0891x; 1.0493x over previous
//
#include <hip/hip_runtime.h>
#include <hip/hip_bf16.h>

// Problem constants
#define BSZ 256   // batch
#define TT  512   // timesteps
#define II  512   // input dim
#define HH  1024  // hidden
#define OO  128   // output
#define BH  262144  // BSZ*HH

// GEMM tiling
#define BM 128
#define BN 128
#define BK 32
#define LDA 40  // padded LDS row stride (shorts): 80B rows, 16B-aligned, 2-way bank alias (free per m136)

typedef short bfrag8 __attribute__((ext_vector_type(8)));
typedef float f32x4  __attribute__((ext_vector_type(4)));
typedef short s16x4  __attribute__((ext_vector_type(4)));

__device__ __forceinline__ unsigned short f2bf(float f) {
    union { float f; unsigned int u; } c; c.f = f;
    unsigned int u = c.u;
    unsigned int r = u + 0x7fffu + ((u >> 16) & 1u);  // RNE
    return (unsigned short)(r >> 16);
}
__device__ __forceinline__ float bf2f(unsigned short h) {
    union { unsigned int u; float f; } c; c.u = ((unsigned int)h) << 16;
    return c.f;
}

// Split a float pair into bf16 hi/lo pairs using packed cvt (v_cvt_pk_bf16_f32)
__device__ __forceinline__ void split2(float f0, float f1, s16x4* hi_dst, s16x4* lo_dst, int off) {
    __hip_bfloat162 h2 = __float22bfloat162_rn(make_float2(f0, f1));
    float r0 = f0 - __bfloat162float(h2.x);
    float r1 = f1 - __bfloat162float(h2.y);
    __hip_bfloat162 l2 = __float22bfloat162_rn(make_float2(r0, r1));
    union { __hip_bfloat162 b; int i; } ch, cl;
    ch.b = h2; cl.b = l2;
    ((int*)hi_dst)[off] = ch.i;
    ((int*)lo_dst)[off] = cl.i;
}

// ---------------------------------------------------------------------------
// Fused setup: split W_branch (NB,I,HB) fp32 -> W_hiT/W_loT [h][i] bf16, and
// init scan state (ws is poisoned each call).
// ---------------------------------------------------------------------------
__global__ __launch_bounds__(256) void setup_k(const float* __restrict__ Wb,
                                               const float* __restrict__ v0,
                                               unsigned short* __restrict__ Whi,
                                               unsigned short* __restrict__ Wlo,
                                               float* __restrict__ dS, float* __restrict__ vS,
                                               float* __restrict__ sS, float* __restrict__ aS) {
    int idx = blockIdx.x * 256 + threadIdx.x;      // 0..524287  (NB*I*HB)
    int n = idx >> 17;                              // I*HB = 131072
    int rem = idx & 131071;
    int i = rem >> 8;                               // HB = 256
    int o = rem & 255;
    int h = (n << 8) + o;
    float w = Wb[idx];
    unsigned short hi = f2bf(w);
    float fh = bf2f(hi);
    unsigned short lo = f2bf(w - fh);
    Whi[(size_t)h * II + i] = hi;
    Wlo[(size_t)h * II + i] = lo;
    if (idx < BH) {
        dS[idx] = 0.0f; vS[idx] = v0[idx]; sS[idx] = 0.0f; aS[idx] = 0.0f;
    }
}

// ---------------------------------------------------------------------------
// Split-bf16 GEMM: U[tl][b][h] = sum_i X[b, t0+tl, i] * W[i][h]
// m = b*Tc + tl (b-major within chunk). 3-product fp32 emulation via bf16 MFMA.
// NOTE: no min-waves launch bound — (256,4) forced VGPR 64 + scratch spills
// (WRITE_SIZE 512->894 MiB, gemm 508->635 us). 3 blocks/CU is the real cap
// (VGPR 76 + 64 acc regs in the unified file).
// ---------------------------------------------------------------------------
__global__ __launch_bounds__(256) void gemm_split(
    const float* __restrict__ X, const unsigned short* __restrict__ Whi,
    const unsigned short* __restrict__ Wlo, float* __restrict__ U,
    int t0, int lgTc)
{
    __shared__ __align__(16) short Ah[BM * LDA];
    __shared__ __align__(16) short Al[BM * LDA];
    __shared__ __align__(16) short Bh[BN * LDA];
    __shared__ __align__(16) short Bl[BN * LDA];

    const int n_tile = blockIdx.x;          // 0..7  (fastest -> XCD-pinned column)
    const int m_tile = blockIdx.y;
    const int m0 = m_tile * BM;
    const int h0 = n_tile * BN;
    const int tid = threadIdx.x;
    const int lane = tid & 63;
    const int wave = tid >> 6;
    const int wm = wave & 1, wn = wave >> 1;
    const int l16 = lane & 15, q = lane >> 4;

    f32x4 acc[4][4];
#pragma unroll
    for (int i = 0; i < 4; ++i)
#pragma unroll
        for (int j = 0; j < 4; ++j)
#pragma unroll
            for (int r = 0; r < 4; ++r) acc[i][j][r] = 0.0f;

    // staging index precompute
    const int fr = tid & 7;        // float4 index within A row (8 per 32-float row)
    const int r0 = tid >> 3;       // 0..31
    const int cB = tid & 3;        // 16B chunk within B row (4 per 64B row)
    const int nB = tid >> 2;       // 0..63

    for (int k0 = 0; k0 < II; k0 += BK) {
        // ---- stage A (fp32 -> bf16 hi/lo in-register, packed cvt) ----
#pragma unroll
        for (int p = 0; p < 4; ++p) {
            int r = r0 + p * 32;
            int m = m0 + r;
            int bb = m >> lgTc;
            int tl = m - (bb << lgTc);
            const float4* src = (const float4*)(X + ((size_t)(bb * TT + t0 + tl)) * II + k0 + fr * 4);
            float4 val = *src;
            s16x4 hi4, lo4;
            split2(val.x, val.y, &hi4, &lo4, 0);
            split2(val.z, val.w, &hi4, &lo4, 1);
            *(s16x4*)&Ah[r * LDA + fr * 4] = hi4;
            *(s16x4*)&Al[r * LDA + fr * 4] = lo4;
        }
        // ---- stage B (pure copy, pre-split/transposed) ----
#pragma unroll
        for (int p = 0; p < 2; ++p) {
            int n = nB + p * 64;
            *(uint4*)&Bh[n * LDA + cB * 8] = *(const uint4*)(Whi + (size_t)(h0 + n) * II + k0 + cB * 8);
            *(uint4*)&Bl[n * LDA + cB * 8] = *(const uint4*)(Wlo + (size_t)(h0 + n) * II + k0 + cB * 8);
        }
        __syncthreads();

        bfrag8 ah[4], al[4], bh[4], bl[4];
#pragma unroll
        for (int i = 0; i < 4; ++i) {
            int ra = (wm * 64 + i * 16 + l16) * LDA + q * 8;
            ah[i] = *(const bfrag8*)&Ah[ra];
            al[i] = *(const bfrag8*)&Al[ra];
            int rb = (wn * 64 + i * 16 + l16) * LDA + q * 8;
            bh[i] = *(const bfrag8*)&Bh[rb];
            bl[i] = *(const bfrag8*)&Bl[rb];
        }
#pragma unroll
        for (int im = 0; im < 4; ++im)
#pragma unroll
            for (int in = 0; in < 4; ++in) {
                f32x4 c = acc[im][in];
                c = __builtin_amdgcn_mfma_f32_16x16x32_bf16(ah[im], bh[in], c, 0, 0, 0);
                c = __builtin_amdgcn_mfma_f32_16x16x32_bf16(ah[im], bl[in], c, 0, 0, 0);
                c = __builtin_amdgcn_mfma_f32_16x16x32_bf16(al[im], bh[in], c, 0, 0, 0);
                acc[im][in] = c;
            }
        __syncthreads();
    }

    // epilogue: C/D layout col = lane&15, row = (lane>>4)*4 + r
#pragma unroll
    for (int im = 0; im < 4; ++im) {
        int rowb = wm * 64 + im * 16 + q * 4;
#pragma unroll
        for (int r = 0; r < 4; ++r) {
            int m = m0 + rowb + r;
            int bb = m >> lgTc;
            int tl = m - (bb << lgTc);
            size_t base = ((size_t)tl * BSZ + bb) * HH + h0 + wn * 64 + l16;
#pragma unroll
            for (int in = 0; in < 4; ++in)
                U[base + in * 16] = acc[im][in][r];
        }
    }
}

// ---------------------------------------------------------------------------
// Scan chunk: one thread per 4 consecutive (b,h); float4 loads, depth-8
// software pipeline. With Tc=128 the U chunk (128 MiB) is L3-resident:
// loads should be ~250-cyc L3 hits, FETCH_SIZE ~ 0.
// ---------------------------------------------------------------------------
__global__ __launch_bounds__(256) void scan_chunk(const float4* __restrict__ U4,
    const float* __restrict__ tau_n, const float* __restrict__ tau_m,
    float4* __restrict__ dS, float4* __restrict__ vS,
    float4* __restrict__ sS, float4* __restrict__ aS, int t0, int Tc)
{
    int tix = blockIdx.x * 256 + threadIdx.x;  // float4 index: 0..65535
    int hb = (tix << 2) & (HH - 1);
    float beta[4], alpha[4], ob[4], oa[4];
#pragma unroll
    for (int j = 0; j < 4; ++j) {
        beta[j]  = 1.0f / (1.0f + __expf(-tau_n[hb + j]));
        alpha[j] = 1.0f / (1.0f + __expf(-tau_m[hb + j]));
        ob[j] = 1.0f - beta[j]; oa[j] = 1.0f - alpha[j];
    }
    float4 d4 = dS[tix], v4 = vS[tix], s4 = sS[tix], a4 = aS[tix];
    float dd[4] = { d4.x, d4.y, d4.z, d4.w };
    float vv[4] = { v4.x, v4.y, v4.z, v4.w };
    float ss[4] = { s4.x, s4.y, s4.z, s4.w };
    float aa[4] = { a4.x, a4.y, a4.z, a4.w };

    const float4* Up = U4 + tix;   // per-t stride = BH/4 = 65536 float4
    float4 ubuf[8];
#pragma unroll
    for (int j = 0; j < 8; ++j) ubuf[j] = Up[(size_t)j << 16];

    for (int tg = 0; tg < Tc; tg += 8) {
#pragma unroll
        for (int j = 0; j < 8; ++j) {
            float4 u4 = ubuf[j];
            int tn = tg + 8 + j;
            if (tn < Tc) ubuf[j] = Up[(size_t)tn << 16];
            float uu[4] = { u4.x, u4.y, u4.z, u4.w };
            float msk = ((t0 + tg + j) >= (TT / 2)) ? 1.0f : 0.0f;
#pragma unroll
            for (int c = 0; c < 4; ++c) {
                dd[c] = beta[c] * dd[c] + ob[c] * uu[c];
                vv[c] = alpha[c] * vv[c] + oa[c] * dd[c] - ss[c];  // prev s; V_TH=1
                ss[c] = (vv[c] > 1.0f) ? 1.0f : 0.0f;
                aa[c] += msk * ss[c];
            }
        }
    }
    dS[tix] = make_float4(dd[0], dd[1], dd[2], dd[3]);
    vS[tix] = make_float4(vv[0], vv[1], vv[2], vv[3]);
    sS[tix] = make_float4(ss[0], ss[1], ss[2], ss[3]);
    aS[tix] = make_float4(aa[0], aa[1], aa[2], aa[3]);
}

// ---------------------------------------------------------------------------
// out[b][o] = sum_h acc[b][h] * W_out[h][o] + b_out[o]
// 256 threads: (o:128) x (h-half:2), LDS combine.
// ---------------------------------------------------------------------------
__global__ __launch_bounds__(256) void out_gemm(const float* __restrict__ acc,
    const float* __restrict__ Wout, const float* __restrict__ bout,
    float* __restrict__ out)
{
    __shared__ float a_s[HH];
    __shared__ float partial[OO];
    int b = blockIdx.x;
    int o = threadIdx.x & (OO - 1);
    int half = threadIdx.x >> 7;
    for (int i = threadIdx.x; i < HH; i += 256) a_s[i] = acc[b * HH + i];
    __syncthreads();
    float sum = half ? 0.0f : bout[o];
    const float* Wp = Wout + (size_t)half * 512 * OO + o;
    const float* ap = a_s + half * 512;
#pragma unroll 8
    for (int h = 0; h < 512; ++h) sum = fmaf(ap[h], Wp[(size_t)h * OO], sum);
    if (half) partial[o] = sum;
    __syncthreads();
    if (!half) out[b * OO + o] = sum + partial[o];
}

// ---------------------------------------------------------------------------
extern "C" void kernel_launch(void* const* d_in, const int* in_sizes, int n_in,
                              void* d_out, int out_size, void* d_ws, size_t ws_size,
                              hipStream_t stream) {
    const float* x     = (const float*)d_in[0];
    const float* v0    = (const float*)d_in[1];
    const float* Wb    = (const float*)d_in[2];
    const float* tau_n = (const float*)d_in[3];
    const float* tau_m = (const float*)d_in[4];
    const float* Wout  = (const float*)d_in[5];
    const float* bout  = (const float*)d_in[6];
    float* out = (float*)d_out;

    // workspace layout (1 MiB units)
    char* ws = (char*)d_ws;
    unsigned short* Whi = (unsigned short*)(ws);                 // 1 MiB
    unsigned short* Wlo = (unsigned short*)(ws + (1ll << 20));   // 1 MiB
    float* dS = (float*)(ws + (2ll << 20));
    float* vS = (float*)(ws + (3ll << 20));
    float* sS = (float*)(ws + (4ll << 20));
    float* aS = (float*)(ws + (5ll << 20));
    float* U  = (float*)(ws + (6ll << 20));

    // Tc=128: U chunk = 128 MiB, fits L3 (256 MiB) with room -> gemm writes
    // stay dirty-resident, scan reads are L3 hits, U never round-trips HBM.
    long long avail = (long long)ws_size - (6ll << 20);
    int Tc = 128;
    while (Tc > 16 && (long long)Tc * (1ll << 20) > avail) Tc >>= 1;
    int lgTc = 31 - __builtin_clz((unsigned)Tc);

    setup_k<<<2048, 256, 0, stream>>>(Wb, v0, Whi, Wlo, dS, vS, sS, aS);

    for (int t0 = 0; t0 < TT; t0 += Tc) {
        dim3 grid(HH / BN, (BSZ * Tc) / BM);  // n fastest -> XCD-pinned columns, L3 reuse of X
        gemm_split<<<grid, 256, 0, stream>>>(x, Whi, Wlo, U, t0, lgTc);
        scan_chunk<<<BH / 1024, 256, 0, stream>>>((const float4*)U, tau_n, tau_m,
                                                  (float4*)dS, (float4*)vS, (float4*)sS, (float4*)aS,
                                                  t0, Tc);
    }
    out_gemm<<<BSZ, 256, 0, stream>>>(aS, Wout, bout, out);
}

// Round 4
// 890.843 us; speedup vs baseline: 1.2029x; 1.1045x over previous
//
#include <hip/hip_runtime.h>
#include <hip/hip_bf16.h>

// Problem constants
#define BSZ 256   // batch
#define TT  512   // timesteps
#define II  512   // input dim
#define HH  1024  // hidden
#define OO  128   // output
#define BH  262144  // BSZ*HH

// GEMM tiling
#define BM 128
#define BN 128
#define BK 32
#define LDA 40  // padded LDS row stride (shorts): 80B rows, 16B-aligned, 2-way bank alias (free per m136)

typedef short bfrag8 __attribute__((ext_vector_type(8)));
typedef float f32x4  __attribute__((ext_vector_type(4)));
typedef short s16x4  __attribute__((ext_vector_type(4)));

__device__ __forceinline__ unsigned short f2bf(float f) {
    union { float f; unsigned int u; } c; c.f = f;
    unsigned int u = c.u;
    unsigned int r = u + 0x7fffu + ((u >> 16) & 1u);  // RNE
    return (unsigned short)(r >> 16);
}
__device__ __forceinline__ float bf2f(unsigned short h) {
    union { unsigned int u; float f; } c; c.u = ((unsigned int)h) << 16;
    return c.f;
}

// Split a float pair into bf16 hi/lo pairs using packed cvt (v_cvt_pk_bf16_f32)
__device__ __forceinline__ void split2(float f0, float f1, s16x4* hi_dst, s16x4* lo_dst, int off) {
    __hip_bfloat162 h2 = __float22bfloat162_rn(make_float2(f0, f1));
    float r0 = f0 - __bfloat162float(h2.x);
    float r1 = f1 - __bfloat162float(h2.y);
    __hip_bfloat162 l2 = __float22bfloat162_rn(make_float2(r0, r1));
    union { __hip_bfloat162 b; int i; } ch, cl;
    ch.b = h2; cl.b = l2;
    ((int*)hi_dst)[off] = ch.i;
    ((int*)lo_dst)[off] = cl.i;
}

// ---------------------------------------------------------------------------
// Fused setup: split W_branch (NB,I,HB) fp32 -> W_hiT/W_loT [h][i] bf16, and
// init scan state (ws is poisoned each call).
// ---------------------------------------------------------------------------
__global__ __launch_bounds__(256) void setup_k(const float* __restrict__ Wb,
                                               const float* __restrict__ v0,
                                               unsigned short* __restrict__ Whi,
                                               unsigned short* __restrict__ Wlo,
                                               float* __restrict__ dS, float* __restrict__ vS,
                                               float* __restrict__ sS, float* __restrict__ aS) {
    int idx = blockIdx.x * 256 + threadIdx.x;      // 0..524287  (NB*I*HB)
    int n = idx >> 17;                              // I*HB = 131072
    int rem = idx & 131071;
    int i = rem >> 8;                               // HB = 256
    int o = rem & 255;
    int h = (n << 8) + o;
    float w = Wb[idx];
    unsigned short hi = f2bf(w);
    float fh = bf2f(hi);
    unsigned short lo = f2bf(w - fh);
    Whi[(size_t)h * II + i] = hi;
    Wlo[(size_t)h * II + i] = lo;
    if (idx < BH) {
        dS[idx] = 0.0f; vS[idx] = v0[idx]; sS[idx] = 0.0f; aS[idx] = 0.0f;
    }
}

// ---------------------------------------------------------------------------
// Split-bf16 GEMM: U[tl][b][h] = sum_i X[b, t0+tl, i] * W[i][h]
// m = b*Tc + tl (b-major within chunk). 3-product fp32 emulation via bf16 MFMA.
// __launch_bounds__(256,2): VGPR 76 (+64 acc) -> 3 blocks/CU. (256,4) forced
// spills (R2: WRITE 512->894 MiB); no bound -> VGPR 96 -> 2 blocks/CU (R3).
// ---------------------------------------------------------------------------
__global__ __launch_bounds__(256, 2) void gemm_split(
    const float* __restrict__ X, const unsigned short* __restrict__ Whi,
    const unsigned short* __restrict__ Wlo, float* __restrict__ U,
    int t0, int lgTc)
{
    __shared__ __align__(16) short Ah[BM * LDA];
    __shared__ __align__(16) short Al[BM * LDA];
    __shared__ __align__(16) short Bh[BN * LDA];
    __shared__ __align__(16) short Bl[BN * LDA];

    const int n_tile = blockIdx.x;          // 0..7  (fastest -> XCD-pinned column)
    const int m_tile = blockIdx.y;
    const int m0 = m_tile * BM;
    const int h0 = n_tile * BN;
    const int tid = threadIdx.x;
    const int lane = tid & 63;
    const int wave = tid >> 6;
    const int wm = wave & 1, wn = wave >> 1;
    const int l16 = lane & 15, q = lane >> 4;

    f32x4 acc[4][4];
#pragma unroll
    for (int i = 0; i < 4; ++i)
#pragma unroll
        for (int j = 0; j < 4; ++j)
#pragma unroll
            for (int r = 0; r < 4; ++r) acc[i][j][r] = 0.0f;

    // staging index precompute
    const int fr = tid & 7;        // float4 index within A row (8 per 32-float row)
    const int r0 = tid >> 3;       // 0..31
    const int cB = tid & 3;        // 16B chunk within B row (4 per 64B row)
    const int nB = tid >> 2;       // 0..63

    for (int k0 = 0; k0 < II; k0 += BK) {
        // ---- stage A (fp32 -> bf16 hi/lo in-register, packed cvt) ----
#pragma unroll
        for (int p = 0; p < 4; ++p) {
            int r = r0 + p * 32;
            int m = m0 + r;
            int bb = m >> lgTc;
            int tl = m - (bb << lgTc);
            const float4* src = (const float4*)(X + ((size_t)(bb * TT + t0 + tl)) * II + k0 + fr * 4);
            float4 val = *src;
            s16x4 hi4, lo4;
            split2(val.x, val.y, &hi4, &lo4, 0);
            split2(val.z, val.w, &hi4, &lo4, 1);
            *(s16x4*)&Ah[r * LDA + fr * 4] = hi4;
            *(s16x4*)&Al[r * LDA + fr * 4] = lo4;
        }
        // ---- stage B (pure copy, pre-split/transposed) ----
#pragma unroll
        for (int p = 0; p < 2; ++p) {
            int n = nB + p * 64;
            *(uint4*)&Bh[n * LDA + cB * 8] = *(const uint4*)(Whi + (size_t)(h0 + n) * II + k0 + cB * 8);
            *(uint4*)&Bl[n * LDA + cB * 8] = *(const uint4*)(Wlo + (size_t)(h0 + n) * II + k0 + cB * 8);
        }
        __syncthreads();

        bfrag8 ah[4], al[4], bh[4], bl[4];
#pragma unroll
        for (int i = 0; i < 4; ++i) {
            int ra = (wm * 64 + i * 16 + l16) * LDA + q * 8;
            ah[i] = *(const bfrag8*)&Ah[ra];
            al[i] = *(const bfrag8*)&Al[ra];
            int rb = (wn * 64 + i * 16 + l16) * LDA + q * 8;
            bh[i] = *(const bfrag8*)&Bh[rb];
            bl[i] = *(const bfrag8*)&Bl[rb];
        }
#pragma unroll
        for (int im = 0; im < 4; ++im)
#pragma unroll
            for (int in = 0; in < 4; ++in) {
                f32x4 c = acc[im][in];
                c = __builtin_amdgcn_mfma_f32_16x16x32_bf16(ah[im], bh[in], c, 0, 0, 0);
                c = __builtin_amdgcn_mfma_f32_16x16x32_bf16(ah[im], bl[in], c, 0, 0, 0);
                c = __builtin_amdgcn_mfma_f32_16x16x32_bf16(al[im], bh[in], c, 0, 0, 0);
                acc[im][in] = c;
            }
        __syncthreads();
    }

    // epilogue: C/D layout col = lane&15, row = (lane>>4)*4 + r
#pragma unroll
    for (int im = 0; im < 4; ++im) {
        int rowb = wm * 64 + im * 16 + q * 4;
#pragma unroll
        for (int r = 0; r < 4; ++r) {
            int m = m0 + rowb + r;
            int bb = m >> lgTc;
            int tl = m - (bb << lgTc);
            size_t base = ((size_t)tl * BSZ + bb) * HH + h0 + wn * 64 + l16;
#pragma unroll
            for (int in = 0; in < 4; ++in)
                U[base + in * 16] = acc[im][in][r];
        }
    }
}

// ---------------------------------------------------------------------------
// Scan: one thread per (b,h) scalar -> 262144 threads = 1024 blocks =
// 16 waves/CU (4x the float4 version's TLP). Depth-16 register pipeline,
// drain tail outside the hot loop (no conditional load in steady state).
// In-flight: 16 waves x 16 x 256 B = 64 KiB/CU >> 9 KiB needed at 900 cyc.
// ---------------------------------------------------------------------------
__global__ __launch_bounds__(256) void scan_chunk(const float* __restrict__ U,
    const float* __restrict__ tau_n, const float* __restrict__ tau_m,
    float* __restrict__ dS, float* __restrict__ vS,
    float* __restrict__ sS, float* __restrict__ aS, int t0, int Tc)
{
    int idx = blockIdx.x * 256 + threadIdx.x;  // b*H + h
    int h = idx & (HH - 1);
    float beta  = 1.0f / (1.0f + __expf(-tau_n[h]));
    float alpha = 1.0f / (1.0f + __expf(-tau_m[h]));
    float ob = 1.0f - beta, oa = 1.0f - alpha;
    float dd = dS[idx], vv = vS[idx], ss = sS[idx], aa = aS[idx];
    const float* Up = U + idx;   // per-t stride = BH floats

    float u[16];
#pragma unroll
    for (int j = 0; j < 16; ++j) u[j] = Up[(size_t)j << 18];

    int tg = 0;
    for (; tg + 16 < Tc; tg += 16) {
#pragma unroll
        for (int j = 0; j < 16; ++j) {
            float uu = u[j];
            u[j] = Up[(size_t)(tg + 16 + j) << 18];
            float msk = ((t0 + tg + j) >= (TT / 2)) ? 1.0f : 0.0f;
            dd = beta * dd + ob * uu;
            vv = alpha * vv + oa * dd - ss;   // prev s; V_TH=1
            ss = (vv > 1.0f) ? 1.0f : 0.0f;
            aa += msk * ss;
        }
    }
#pragma unroll
    for (int j = 0; j < 16; ++j) {           // drain
        float uu = u[j];
        float msk = ((t0 + tg + j) >= (TT / 2)) ? 1.0f : 0.0f;
        dd = beta * dd + ob * uu;
        vv = alpha * vv + oa * dd - ss;
        ss = (vv > 1.0f) ? 1.0f : 0.0f;
        aa += msk * ss;
    }
    dS[idx] = dd; vS[idx] = vv; sS[idx] = ss; aS[idx] = aa;
}

// ---------------------------------------------------------------------------
// out[b][o] = sum_h acc[b][h] * W_out[h][o] + b_out[o]
// 256 threads: (o:128) x (h-half:2), LDS combine.
// ---------------------------------------------------------------------------
__global__ __launch_bounds__(256) void out_gemm(const float* __restrict__ acc,
    const float* __restrict__ Wout, const float* __restrict__ bout,
    float* __restrict__ out)
{
    __shared__ float a_s[HH];
    __shared__ float partial[OO];
    int b = blockIdx.x;
    int o = threadIdx.x & (OO - 1);
    int half = threadIdx.x >> 7;
    for (int i = threadIdx.x; i < HH; i += 256) a_s[i] = acc[b * HH + i];
    __syncthreads();
    float sum = half ? 0.0f : bout[o];
    const float* Wp = Wout + (size_t)half * 512 * OO + o;
    const float* ap = a_s + half * 512;
#pragma unroll 8
    for (int h = 0; h < 512; ++h) sum = fmaf(ap[h], Wp[(size_t)h * OO], sum);
    if (half) partial[o] = sum;
    __syncthreads();
    if (!half) out[b * OO + o] = sum + partial[o];
}

// ---------------------------------------------------------------------------
extern "C" void kernel_launch(void* const* d_in, const int* in_sizes, int n_in,
                              void* d_out, int out_size, void* d_ws, size_t ws_size,
                              hipStream_t stream) {
    const float* x     = (const float*)d_in[0];
    const float* v0    = (const float*)d_in[1];
    const float* Wb    = (const float*)d_in[2];
    const float* tau_n = (const float*)d_in[3];
    const float* tau_m = (const float*)d_in[4];
    const float* Wout  = (const float*)d_in[5];
    const float* bout  = (const float*)d_in[6];
    float* out = (float*)d_out;

    // workspace layout (1 MiB units)
    char* ws = (char*)d_ws;
    unsigned short* Whi = (unsigned short*)(ws);                 // 1 MiB
    unsigned short* Wlo = (unsigned short*)(ws + (1ll << 20));   // 1 MiB
    float* dS = (float*)(ws + (2ll << 20));
    float* vS = (float*)(ws + (3ll << 20));
    float* sS = (float*)(ws + (4ll << 20));
    float* aS = (float*)(ws + (5ll << 20));
    float* U  = (float*)(ws + (6ll << 20));

    // Single full-T chunk preferred: U writes drain to HBM regardless (R3:
    // WRITE_SIZE == chunk size), so chunking only buys gemm tail waste
    // (2048-block grids quantize to 3 rounds at 3 blocks/CU). Shrink Tc only
    // if ws is too small.
    long long avail = (long long)ws_size - (6ll << 20);
    int Tc = 512;
    while (Tc > 16 && (long long)Tc * (1ll << 20) > avail) Tc >>= 1;
    int lgTc = 31 - __builtin_clz((unsigned)Tc);

    setup_k<<<2048, 256, 0, stream>>>(Wb, v0, Whi, Wlo, dS, vS, sS, aS);

    for (int t0 = 0; t0 < TT; t0 += Tc) {
        dim3 grid(HH / BN, (BSZ * Tc) / BM);  // n fastest -> XCD-pinned columns, L3 reuse of X
        gemm_split<<<grid, 256, 0, stream>>>(x, Whi, Wlo, U, t0, lgTc);
        scan_chunk<<<BH / 256, 256, 0, stream>>>(U, tau_n, tau_m, dS, vS, sS, aS, t0, Tc);
    }
    out_gemm<<<BSZ, 256, 0, stream>>>(aS, Wout, bout, out);
}